// Round 2
// baseline (691.784 us; speedup 1.0000x reference)
//
#include <hip/hip_runtime.h>
#include <hip/hip_bf16.h>

#define N_NODES  50000
#define N_EDGES  800000
#define NDIM_IN  64
#define EDIMS    64
#define NDIM_OUT 128

typedef __bf16 bf16;
typedef bf16  bf16x8 __attribute__((ext_vector_type(8)));
typedef float f32x4  __attribute__((ext_vector_type(4)));

// ---------------------------------------------------------------------------
// Runtime dtype detection (harness dtype is ambiguous; we guard both ways).
// ---------------------------------------------------------------------------
__device__ __forceinline__ bool detect_f32(const void* nfeats) {
    const unsigned short* w = (const unsigned short*)nfeats;
    for (int i = 0; i < 64; i += 2) {
        const int e = (w[i] >> 7) & 0xFF;
        if (e < 100 || e > 134) return true;
    }
    return false;
}
__device__ __forceinline__ bool detect_i64(const int* p) {
    for (int i = 1; i < 64; i += 2) if (p[i] != 0) return false;
    return true;
}

__device__ __forceinline__ bf16x8 load8(const void* p, long off, bool f32) {
    if (f32) {
        const float* q = (const float*)p + off;
        const f32x4 a = *(const f32x4*)q;
        const f32x4 b = *(const f32x4*)(q + 4);
        bf16x8 r;
        #pragma unroll
        for (int u = 0; u < 4; ++u) { r[u] = (bf16)a[u]; r[4 + u] = (bf16)b[u]; }
        return r;
    }
    return *(const bf16x8*)((const bf16*)p + off);
}
__device__ __forceinline__ float loadf(const void* p, int i, bool f32) {
    return f32 ? ((const float*)p)[i] : (float)((const bf16*)p)[i];
}
__device__ __forceinline__ void storef(void* p, int i, float v, bool f32) {
    if (f32) ((float*)p)[i] = v; else ((bf16*)p)[i] = (bf16)v;
}

// ---------------------------------------------------------------------------
// CSR build step 1: histogram over dst.
// ---------------------------------------------------------------------------
__global__ __launch_bounds__(256) void hist_kernel(const int* __restrict__ dst,
                                                   int* __restrict__ cnt) {
    __shared__ int s_ish;
    if (threadIdx.x == 0) s_ish = detect_i64(dst) ? 1 : 0;
    __syncthreads();
    const int ish = s_ish;
    const int stride = gridDim.x * blockDim.x;
    for (int e = blockIdx.x * blockDim.x + threadIdx.x; e < N_EDGES; e += stride)
        atomicAdd(&cnt[dst[e << ish]], 1);
}

// ---------------------------------------------------------------------------
// CSR build step 2: exclusive scan of counts (padded to 53248 = 1024*52 ints,
// pad region pre-zeroed). int4 loads + shfl wave scans; re-reads from L2 in
// the writeback pass to keep VGPR low at 1024 threads. Writes row_ptr[] and
// resets cnt[] in place to the running cursor for the scatter/gather pass.
// ---------------------------------------------------------------------------
__global__ __launch_bounds__(1024) void scan_kernel(int* __restrict__ cnt,
                                                    int* __restrict__ row_ptr) {
    __shared__ int sw[16];
    const int t    = threadIdx.x;
    const int lane = t & 63;
    const int w    = t >> 6;
    const int base = t * 52;

    int sum = 0;
    #pragma unroll
    for (int j = 0; j < 13; ++j) {
        const int4 q = *(const int4*)(cnt + base + j * 4);
        sum += q.x + q.y + q.z + q.w;
    }
    int s = sum;                               // inclusive scan across wave
    #pragma unroll
    for (int off = 1; off < 64; off <<= 1) {
        const int u = __shfl_up(s, off, 64);
        if (lane >= off) s += u;
    }
    if (lane == 63) sw[w] = s;
    __syncthreads();
    if (t < 16) {
        int x = sw[t];
        #pragma unroll
        for (int off = 1; off < 16; off <<= 1) {
            const int u = __shfl_up(x, off, 16);
            if ((t & 15) >= off) x += u;
        }
        sw[t] = x;
    }
    __syncthreads();
    int run = (w > 0 ? sw[w - 1] : 0) + (s - sum);   // exclusive thread prefix
    #pragma unroll
    for (int j = 0; j < 13; ++j) {
        const int4 q = *(const int4*)(cnt + base + j * 4);
        int4 r;
        r.x = run; run += q.x;
        r.y = run; run += q.y;
        r.z = run; run += q.z;
        r.w = run; run += q.w;
        *(int4*)(row_ptr + base + j * 4) = r;
        *(int4*)(cnt     + base + j * 4) = r;
    }
}

// ---------------------------------------------------------------------------
// CSR build step 3 (dense path): gather + convert + scatter.
// 4 lanes per edge: pre-gathers the FULL concat row [bf16(nfeats[src]) |
// bf16(efeats[e])] (256 B) and scatter-writes it into CSR order. All the
// randomness lands on the WRITE side (latency-insensitive); msg_agg_dense
// then streams A coalesced. One atomic per edge (lane c==0), pos broadcast
// via shfl.
// ---------------------------------------------------------------------------
__global__ __launch_bounds__(256) void gather_kernel(
    const void* __restrict__ nfeats,
    const void* __restrict__ efeats,
    const int*  __restrict__ src,
    const int*  __restrict__ dst,
    int*        __restrict__ cursor,
    bf16*       __restrict__ A)
{
    __shared__ int s_flags;
    const int tid = threadIdx.x;
    if (tid == 0)
        s_flags = (detect_f32(nfeats) ? 1 : 0) | (detect_i64(dst) ? 2 : 0);
    __syncthreads();
    const bool f32 = (s_flags & 1) != 0;
    const int  ish = (s_flags & 2) ? 1 : 0;

    const int lane = tid & 63;
    const int wave = tid >> 6;
    const int c    = lane & 3;    // quarter of the 256 B output row
    const int ei   = lane >> 2;   // edge within group of 16

    const int ngroups = N_EDGES / 16;          // 50000 exact
    const int nw      = gridDim.x * 4;
    for (int g = blockIdx.x * 4 + wave; g < ngroups; g += nw) {
        const int e = g * 16 + ei;
        int pos = 0;
        if (c == 0) pos = atomicAdd(&cursor[dst[(long)e << ish]], 1);
        pos = __shfl(pos, lane & ~3, 64);
        const int s_ = src[(long)e << ish];

        const void* bsrc = (c < 2) ? nfeats : efeats;
        const int   row  = (c < 2) ? s_ : e;
        const int   ko   = (c & 1) * 32;
        bf16* outp = A + (size_t)pos * 128 + c * 32;
        #pragma unroll
        for (int j = 0; j < 4; ++j) {
            const bf16x8 v = load8(bsrc, (long)row * 64 + ko + j * 8, f32);
            *(bf16x8*)(outp + j * 8) = v;
        }
    }
}

// ---------------------------------------------------------------------------
// Dense fused message + aggregate: one wave per dst node, A is the pre-built
// CSR-ordered [E][128] bf16 matrix -> pure streaming reads (16 rows = 4 KB
// contiguous per tile), MFMA, bias+relu, mask pad rows, column-reduce,
// single coalesced h_neigh write. No gathers, no atomics.
// ---------------------------------------------------------------------------
__global__ __launch_bounds__(256) void msg_agg_dense(
    const void* __restrict__ nfeats,      // only for dtype detection
    const bf16* __restrict__ A,
    const void* __restrict__ W_msg,
    const void* __restrict__ b_msg,
    const int*  __restrict__ row_ptr,
    float*      __restrict__ h_neigh)
{
    __shared__ bf16 sWT[128 * 136];
    __shared__ int s_flags;

    const int tid = threadIdx.x;
    if (tid == 0) s_flags = detect_f32(nfeats) ? 1 : 0;
    __syncthreads();
    const bool f32 = (s_flags & 1) != 0;

    #pragma unroll
    for (int it = 0; it < 8; ++it) {
        const int task = it * 256 + tid;
        const int k = task >> 4;
        const int c = task & 15;
        const bf16x8 w = load8(W_msg, k * 128 + c * 8, f32);
        #pragma unroll
        for (int u = 0; u < 8; ++u) sWT[(c * 8 + u) * 136 + k] = w[u];
    }
    __syncthreads();

    const int wave = tid >> 6;
    const int lane = tid & 63;
    const int m    = lane & 15;
    const int quad = lane >> 4;

    float bias[8];
    #pragma unroll
    for (int t = 0; t < 8; ++t) bias[t] = loadf(b_msg, t * 16 + m, f32);

    const int wstride = gridDim.x * 4;
    for (int v = blockIdx.x * 4 + wave; v < N_NODES; v += wstride) {
        const int beg = row_ptr[v];
        const int deg = row_ptr[v + 1] - beg;

        float hacc[8] = {0.f, 0.f, 0.f, 0.f, 0.f, 0.f, 0.f, 0.f};

        for (int T = 0; T * 16 < deg; ++T) {
            const int r0 = T * 16;
            const int sl = (r0 + m < deg) ? (beg + r0 + m) : beg;
            const bf16* ap = A + (size_t)sl * 128 + quad * 8;

            bf16x8 a[4];
            #pragma unroll
            for (int kb = 0; kb < 4; ++kb)
                a[kb] = *(const bf16x8*)(ap + kb * 32);

            #pragma unroll
            for (int t = 0; t < 8; ++t) {
                f32x4 acc = {0.f, 0.f, 0.f, 0.f};
                const bf16* bp = sWT + (t * 16 + m) * 136 + quad * 8;
                #pragma unroll
                for (int kb = 0; kb < 4; ++kb)
                    acc = __builtin_amdgcn_mfma_f32_16x16x32_bf16(
                              a[kb], *(const bf16x8*)(bp + kb * 32), acc, 0, 0, 0);
                float part = 0.f;
                #pragma unroll
                for (int i = 0; i < 4; ++i) {
                    float val = acc[i] + bias[t];
                    val = val > 0.f ? val : 0.f;
                    if (r0 + quad * 4 + i < deg) part += val;
                }
                hacc[t] += part;
            }
        }

        #pragma unroll
        for (int t = 0; t < 8; ++t) {
            float s = hacc[t];
            s += __shfl_xor(s, 16, 64);
            s += __shfl_xor(s, 32, 64);
            hacc[t] = s;
        }

        const float lo = quad < 2 ? (quad == 0 ? hacc[0] : hacc[1])
                                  : (quad == 2 ? hacc[2] : hacc[3]);
        const float hi = quad < 2 ? (quad == 0 ? hacc[4] : hacc[5])
                                  : (quad == 2 ? hacc[6] : hacc[7]);
        h_neigh[v * 128 + lane]      = lo;
        h_neigh[v * 128 + 64 + lane] = hi;
    }
}

// ---------------------------------------------------------------------------
// Fallback CSR path (verified round-1): scatter edge ids, gather in msg_agg.
// ---------------------------------------------------------------------------
__global__ __launch_bounds__(256) void scatter_kernel(const int* __restrict__ src,
                                                      const int* __restrict__ dst,
                                                      int* __restrict__ cursor,
                                                      int* __restrict__ eid,
                                                      int* __restrict__ srcs) {
    __shared__ int s_ish;
    if (threadIdx.x == 0) s_ish = detect_i64(dst) ? 1 : 0;
    __syncthreads();
    const int ish = s_ish;
    const int stride = gridDim.x * blockDim.x;
    for (int e = blockIdx.x * blockDim.x + threadIdx.x; e < N_EDGES; e += stride) {
        const int d = dst[(long)e << ish];
        const int pos = atomicAdd(&cursor[d], 1);
        eid[pos]  = e;
        srcs[pos] = src[(long)e << ish];
    }
}

__global__ __launch_bounds__(256) void msg_agg_kernel(
    const void* __restrict__ nfeats,
    const void* __restrict__ efeats,
    const void* __restrict__ W_msg,
    const void* __restrict__ b_msg,
    const int*  __restrict__ row_ptr,
    const int*  __restrict__ eid,
    const int*  __restrict__ srcs,
    float*      __restrict__ h_neigh)
{
    __shared__ bf16 sWT[128 * 136];
    __shared__ int s_flags;

    const int tid = threadIdx.x;
    if (tid == 0) s_flags = detect_f32(nfeats) ? 1 : 0;
    __syncthreads();
    const bool f32 = (s_flags & 1) != 0;

    #pragma unroll
    for (int it = 0; it < 8; ++it) {
        const int task = it * 256 + tid;
        const int k = task >> 4;
        const int c = task & 15;
        const bf16x8 w = load8(W_msg, k * 128 + c * 8, f32);
        #pragma unroll
        for (int u = 0; u < 8; ++u) sWT[(c * 8 + u) * 136 + k] = w[u];
    }
    __syncthreads();

    const int wave = tid >> 6;
    const int lane = tid & 63;
    const int m    = lane & 15;
    const int quad = lane >> 4;

    float bias[8];
    #pragma unroll
    for (int t = 0; t < 8; ++t) bias[t] = loadf(b_msg, t * 16 + m, f32);

    const int wstride = gridDim.x * 4;
    for (int v = blockIdx.x * 4 + wave; v < N_NODES; v += wstride) {
        const int beg = row_ptr[v];
        const int deg = row_ptr[v + 1] - beg;

        float hacc[8] = {0.f, 0.f, 0.f, 0.f, 0.f, 0.f, 0.f, 0.f};

        for (int T = 0; T * 16 < deg; ++T) {
            const int r0 = T * 16;
            const int sl = (r0 + m < deg) ? (beg + r0 + m) : beg;
            const int s  = srcs[sl];
            const int e  = eid[sl];

            bf16x8 a[4];
            a[0] = load8(nfeats, (long)s * 64 +      quad * 8, f32);
            a[1] = load8(nfeats, (long)s * 64 + 32 + quad * 8, f32);
            a[2] = load8(efeats, (long)e * 64 +      quad * 8, f32);
            a[3] = load8(efeats, (long)e * 64 + 32 + quad * 8, f32);

            #pragma unroll
            for (int t = 0; t < 8; ++t) {
                f32x4 acc = {0.f, 0.f, 0.f, 0.f};
                const bf16* bp = sWT + (t * 16 + m) * 136 + quad * 8;
                #pragma unroll
                for (int kb = 0; kb < 4; ++kb)
                    acc = __builtin_amdgcn_mfma_f32_16x16x32_bf16(
                              a[kb], *(const bf16x8*)(bp + kb * 32), acc, 0, 0, 0);
                float part = 0.f;
                #pragma unroll
                for (int i = 0; i < 4; ++i) {
                    float val = acc[i] + bias[t];
                    val = val > 0.f ? val : 0.f;
                    if (r0 + quad * 4 + i < deg) part += val;
                }
                hacc[t] += part;
            }
        }

        #pragma unroll
        for (int t = 0; t < 8; ++t) {
            float s = hacc[t];
            s += __shfl_xor(s, 16, 64);
            s += __shfl_xor(s, 32, 64);
            hacc[t] = s;
        }

        const float lo = quad < 2 ? (quad == 0 ? hacc[0] : hacc[1])
                                  : (quad == 2 ? hacc[2] : hacc[3]);
        const float hi = quad < 2 ? (quad == 0 ? hacc[4] : hacc[5])
                                  : (quad == 2 ? hacc[6] : hacc[7]);
        h_neigh[v * 128 + lane]      = lo;
        h_neigh[v * 128 + 64 + lane] = hi;
    }
}

// ---------------------------------------------------------------------------
// Last-resort fallback (verified round-0): per-edge messages + fp32 atomics.
// ---------------------------------------------------------------------------
__global__ __launch_bounds__(256) void edge_msg_kernel(
    const void* __restrict__ nfeats,
    const void* __restrict__ efeats,
    const void* __restrict__ W_msg,
    const void* __restrict__ b_msg,
    const int*  __restrict__ src,
    const int*  __restrict__ dst,
    float*      __restrict__ h_neigh)
{
    __shared__ bf16 sWT[128 * 136];
    __shared__ int s_flags;

    const int tid = threadIdx.x;
    if (tid == 0)
        s_flags = (detect_f32(nfeats) ? 1 : 0) | (detect_i64(dst) ? 2 : 0);
    __syncthreads();
    const bool f32 = (s_flags & 1) != 0;
    const int  ish = (s_flags & 2) ? 1 : 0;

    #pragma unroll
    for (int it = 0; it < 8; ++it) {
        const int task = it * 256 + tid;
        const int k = task >> 4;
        const int c = task & 15;
        const bf16x8 w = load8(W_msg, k * 128 + c * 8, f32);
        #pragma unroll
        for (int u = 0; u < 8; ++u) sWT[(c * 8 + u) * 136 + k] = w[u];
    }
    __syncthreads();

    const int wave = tid >> 6;
    const int lane = tid & 63;
    const int m    = lane & 15;
    const int quad = lane >> 4;

    const int nchunks = N_EDGES / 64;
    for (int chunk = blockIdx.x; chunk < nchunks; chunk += gridDim.x) {
        const int ebase = chunk * 64 + wave * 16;
        const int e_m   = ebase + m;
        const int s     = src[(long)e_m << ish];

        bf16x8 a[4];
        a[0] = load8(nfeats, (long)s   * 64 +      quad * 8, f32);
        a[1] = load8(nfeats, (long)s   * 64 + 32 + quad * 8, f32);
        a[2] = load8(efeats, (long)e_m * 64 +      quad * 8, f32);
        a[3] = load8(efeats, (long)e_m * 64 + 32 + quad * 8, f32);

        int drow[4];
        #pragma unroll
        for (int i = 0; i < 4; ++i)
            drow[i] = dst[(long)(ebase + quad * 4 + i) << ish] * 128;

        #pragma unroll
        for (int t = 0; t < 8; ++t) {
            f32x4 acc = {0.f, 0.f, 0.f, 0.f};
            const bf16* bp = sWT + (t * 16 + m) * 136 + quad * 8;
            #pragma unroll
            for (int kb = 0; kb < 4; ++kb)
                acc = __builtin_amdgcn_mfma_f32_16x16x32_bf16(
                          a[kb], *(const bf16x8*)(bp + kb * 32), acc, 0, 0, 0);
            const int   n    = t * 16 + m;
            const float bias = loadf(b_msg, n, f32);
            #pragma unroll
            for (int i = 0; i < 4; ++i) {
                float v = acc[i] + bias;
                v = v > 0.f ? v : 0.f;
                unsafeAtomicAdd(h_neigh + drow[i] + n, v);
            }
        }
    }
}

// ---------------------------------------------------------------------------
// Kernel B: out = relu([nfeats, h_neigh] @ W_apply + b_apply), K=192.
// ---------------------------------------------------------------------------
__global__ __launch_bounds__(256) void apply_kernel(
    const void*  __restrict__ nfeats,
    const float* __restrict__ h_neigh,
    const void*  __restrict__ W_apply,
    const void*  __restrict__ b_apply,
    void*        __restrict__ out)
{
    __shared__ bf16 sWT[128 * 200];
    __shared__ int s_flags;

    const int tid = threadIdx.x;
    if (tid == 0) s_flags = detect_f32(nfeats) ? 1 : 0;
    __syncthreads();
    const bool f32 = (s_flags & 1) != 0;

    #pragma unroll
    for (int it = 0; it < 12; ++it) {
        const int task = it * 256 + tid;
        const int k = task >> 4;
        const int c = task & 15;
        const bf16x8 w = load8(W_apply, k * 128 + c * 8, f32);
        #pragma unroll
        for (int u = 0; u < 8; ++u) sWT[(c * 8 + u) * 200 + k] = w[u];
    }
    __syncthreads();

    const int wave = tid >> 6;
    const int lane = tid & 63;
    const int m    = lane & 15;
    const int quad = lane >> 4;

    const int nchunks = (N_NODES + 63) / 64;
    for (int chunk = blockIdx.x; chunk < nchunks; chunk += gridDim.x) {
        const int nbase = chunk * 64 + wave * 16;
        const int nm  = nbase + m;
        const int nmc = nm < N_NODES ? nm : N_NODES - 1;

        bf16x8 a[6];
        a[0] = load8(nfeats, (long)nmc * 64 +      quad * 8, f32);
        a[1] = load8(nfeats, (long)nmc * 64 + 32 + quad * 8, f32);
        #pragma unroll
        for (int kb = 0; kb < 4; ++kb) {
            const float* hp = h_neigh + (size_t)nmc * 128 + kb * 32 + quad * 8;
            const f32x4 p = *(const f32x4*)(hp);
            const f32x4 q = *(const f32x4*)(hp + 4);
            bf16x8 r;
            #pragma unroll
            for (int u = 0; u < 4; ++u) { r[u] = (bf16)p[u]; r[4 + u] = (bf16)q[u]; }
            a[2 + kb] = r;
        }

        #pragma unroll
        for (int t = 0; t < 8; ++t) {
            f32x4 acc = {0.f, 0.f, 0.f, 0.f};
            const bf16* bp = sWT + (t * 16 + m) * 200 + quad * 8;
            #pragma unroll
            for (int kb = 0; kb < 6; ++kb)
                acc = __builtin_amdgcn_mfma_f32_16x16x32_bf16(
                          a[kb], *(const bf16x8*)(bp + kb * 32), acc, 0, 0, 0);
            const int   n    = t * 16 + m;
            const float bias = loadf(b_apply, n, f32);
            #pragma unroll
            for (int i = 0; i < 4; ++i) {
                const int row = nbase + quad * 4 + i;
                if (row < N_NODES) {
                    float v = acc[i] + bias;
                    v = v > 0.f ? v : 0.f;
                    storef(out, row * 128 + n, v, f32);
                }
            }
        }
    }
}

extern "C" void kernel_launch(void* const* d_in, const int* in_sizes, int n_in,
                              void* d_out, int out_size, void* d_ws, size_t ws_size,
                              hipStream_t stream) {
    const void* nfeats  = d_in[0];
    const void* efeats  = d_in[1];
    const void* W_msg   = d_in[2];
    const void* b_msg   = d_in[3];
    const void* W_apply = d_in[4];
    const void* b_apply = d_in[5];
    const int*  src     = (const int*)d_in[6];
    const int*  dst     = (const int*)d_in[7];

    float* h_neigh = (float*)d_ws;                        // 25,600,000 B

    // workspace layout (256B-aligned blocks)
    const size_t SZ_PAD     = 213248;                     // 53248 ints, padded
    const size_t OFF_ROWPTR = 25600000;
    const size_t OFF_CNT    = OFF_ROWPTR + SZ_PAD;        // counts -> cursor
    const size_t OFF_A      = OFF_CNT + SZ_PAD;           // dense path
    const size_t NEED_DENSE = OFF_A + (size_t)N_EDGES * 128 * 2;   // 230.8 MB
    const size_t OFF_EID    = OFF_A;                      // CSR fallback path
    const size_t OFF_SRCS   = OFF_EID + 3200000;
    const size_t NEED_CSR   = OFF_SRCS + 3200000;         // 32.4 MB

    int* row_ptr = (int*)((char*)d_ws + OFF_ROWPTR);
    int* cnt     = (int*)((char*)d_ws + OFF_CNT);

    if (ws_size >= NEED_DENSE) {
        bf16* A = (bf16*)((char*)d_ws + OFF_A);
        hipMemsetAsync(cnt, 0, (size_t)53248 * sizeof(int), stream);
        hist_kernel<<<1024, 256, 0, stream>>>(dst, cnt);
        scan_kernel<<<1, 1024, 0, stream>>>(cnt, row_ptr);
        gather_kernel<<<1024, 256, 0, stream>>>(nfeats, efeats, src, dst, cnt, A);
        msg_agg_dense<<<1024, 256, 0, stream>>>(nfeats, A, W_msg, b_msg,
                                                row_ptr, h_neigh);
    } else if (ws_size >= NEED_CSR) {
        int* eid  = (int*)((char*)d_ws + OFF_EID);
        int* srcs = (int*)((char*)d_ws + OFF_SRCS);
        hipMemsetAsync(cnt, 0, (size_t)53248 * sizeof(int), stream);
        hist_kernel<<<1024, 256, 0, stream>>>(dst, cnt);
        scan_kernel<<<1, 1024, 0, stream>>>(cnt, row_ptr);
        scatter_kernel<<<1024, 256, 0, stream>>>(src, dst, cnt, eid, srcs);
        msg_agg_kernel<<<1024, 256, 0, stream>>>(nfeats, efeats, W_msg, b_msg,
                                                 row_ptr, eid, srcs, h_neigh);
    } else {
        hipMemsetAsync(h_neigh, 0, (size_t)N_NODES * NDIM_OUT * sizeof(float), stream);
        edge_msg_kernel<<<768, 256, 0, stream>>>(nfeats, efeats, W_msg, b_msg,
                                                 src, dst, h_neigh);
    }

    apply_kernel<<<782, 256, 0, stream>>>(nfeats, h_neigh, W_apply, b_apply, d_out);
}

// Round 3
// 608.114 us; speedup vs baseline: 1.1376x; 1.1376x over previous
//
#include <hip/hip_runtime.h>
#include <hip/hip_bf16.h>

#define N_NODES  50000
#define N_EDGES  800000
#define NDIM_IN  64
#define EDIMS    64
#define NDIM_OUT 128

typedef __bf16 bf16;
typedef bf16  bf16x8 __attribute__((ext_vector_type(8)));
typedef float f32x4  __attribute__((ext_vector_type(4)));

// ---------------------------------------------------------------------------
// Runtime dtype detection (harness dtype is ambiguous; we guard both ways).
// ---------------------------------------------------------------------------
__device__ __forceinline__ bool detect_f32(const void* nfeats) {
    const unsigned short* w = (const unsigned short*)nfeats;
    for (int i = 0; i < 64; i += 2) {
        const int e = (w[i] >> 7) & 0xFF;
        if (e < 100 || e > 134) return true;
    }
    return false;
}
__device__ __forceinline__ bool detect_i64(const int* p) {
    for (int i = 1; i < 64; i += 2) if (p[i] != 0) return false;
    return true;
}

__device__ __forceinline__ bf16x8 load8(const void* p, long off, bool f32) {
    if (f32) {
        const float* q = (const float*)p + off;
        const f32x4 a = *(const f32x4*)q;
        const f32x4 b = *(const f32x4*)(q + 4);
        bf16x8 r;
        #pragma unroll
        for (int u = 0; u < 4; ++u) { r[u] = (bf16)a[u]; r[4 + u] = (bf16)b[u]; }
        return r;
    }
    return *(const bf16x8*)((const bf16*)p + off);
}
__device__ __forceinline__ float loadf(const void* p, long i, bool f32) {
    return f32 ? ((const float*)p)[i] : (float)((const bf16*)p)[i];
}
__device__ __forceinline__ void storef(void* p, long i, float v, bool f32) {
    if (f32) ((float*)p)[i] = v; else ((bf16*)p)[i] = (bf16)v;
}

// ---------------------------------------------------------------------------
// nfeats -> bf16 table (coalesced convert). Makes gather's random reads 128 B
// instead of 256 B and mostly L2-resident (6.4 MB).
// ---------------------------------------------------------------------------
__global__ __launch_bounds__(256) void nf2bf_kernel(const void* __restrict__ nfeats,
                                                    bf16* __restrict__ tbl) {
    __shared__ int s_flags;
    if (threadIdx.x == 0) s_flags = detect_f32(nfeats) ? 1 : 0;
    __syncthreads();
    const bool f32 = (s_flags & 1) != 0;
    const int total  = N_NODES * 64 / 8;          // 400000 chunks of 8
    const int stride = gridDim.x * blockDim.x;
    for (int i = blockIdx.x * blockDim.x + threadIdx.x; i < total; i += stride)
        *(bf16x8*)(tbl + (size_t)i * 8) = load8(nfeats, (long)i * 8, f32);
}

// ---------------------------------------------------------------------------
// CSR build step 1: histogram over dst.
// ---------------------------------------------------------------------------
__global__ __launch_bounds__(256) void hist_kernel(const int* __restrict__ dst,
                                                   int* __restrict__ cnt) {
    __shared__ int s_ish;
    if (threadIdx.x == 0) s_ish = detect_i64(dst) ? 1 : 0;
    __syncthreads();
    const int ish = s_ish;
    const int stride = gridDim.x * blockDim.x;
    for (int e = blockIdx.x * blockDim.x + threadIdx.x; e < N_EDGES; e += stride)
        atomicAdd(&cnt[dst[(long)e << ish]], 1);
}

// ---------------------------------------------------------------------------
// CSR build step 2: exclusive scan of counts (padded to 53248 = 1024*52 ints,
// pad region pre-zeroed). int4 loads + shfl wave scans. Writes row_ptr[] and
// resets cnt[] in place to the running cursor for the gather pass.
// ---------------------------------------------------------------------------
__global__ __launch_bounds__(1024) void scan_kernel(int* __restrict__ cnt,
                                                    int* __restrict__ row_ptr) {
    __shared__ int sw[16];
    const int t    = threadIdx.x;
    const int lane = t & 63;
    const int w    = t >> 6;
    const int base = t * 52;

    int sum = 0;
    #pragma unroll
    for (int j = 0; j < 13; ++j) {
        const int4 q = *(const int4*)(cnt + base + j * 4);
        sum += q.x + q.y + q.z + q.w;
    }
    int s = sum;
    #pragma unroll
    for (int off = 1; off < 64; off <<= 1) {
        const int u = __shfl_up(s, off, 64);
        if (lane >= off) s += u;
    }
    if (lane == 63) sw[w] = s;
    __syncthreads();
    if (t < 16) {
        int x = sw[t];
        #pragma unroll
        for (int off = 1; off < 16; off <<= 1) {
            const int u = __shfl_up(x, off, 16);
            if ((t & 15) >= off) x += u;
        }
        sw[t] = x;
    }
    __syncthreads();
    int run = (w > 0 ? sw[w - 1] : 0) + (s - sum);
    #pragma unroll
    for (int j = 0; j < 13; ++j) {
        const int4 q = *(const int4*)(cnt + base + j * 4);
        int4 r;
        r.x = run; run += q.x;
        r.y = run; run += q.y;
        r.z = run; run += q.z;
        r.w = run; run += q.w;
        *(int4*)(row_ptr + base + j * 4) = r;
        *(int4*)(cnt     + base + j * 4) = r;
    }
}

// ---------------------------------------------------------------------------
// CSR build step 3: gather + convert + scatter, full-line stores.
// 16 lanes per edge, lane q owns 16 B chunk q of the 256 B row -> every store
// instruction writes 4 edges x 256 B contiguous (no partial-line RMW).
// q<8 reads bf16 nfeats table (128 B random), q>=8 reads efeats coalesced.
// ---------------------------------------------------------------------------
__global__ __launch_bounds__(256) void gather_kernel(
    const void* __restrict__ nfsrc,     // bf16 table (tbl=1) or raw nfeats
    const void* __restrict__ efeats,
    const int*  __restrict__ src,
    const int*  __restrict__ dst,
    int*        __restrict__ cursor,
    bf16*       __restrict__ A,
    const int   tbl)
{
    __shared__ int s_flags;
    const int tid = threadIdx.x;
    if (tid == 0)
        s_flags = (detect_f32(efeats) ? 1 : 0) | (detect_i64(dst) ? 2 : 0);
    __syncthreads();
    const bool f32 = (s_flags & 1) != 0;
    const int  ish = (s_flags & 2) ? 1 : 0;

    const int lane = tid & 63;
    const int wave = tid >> 6;
    const int q    = lane & 15;   // 16 B chunk of the 256 B output row
    const int ei   = lane >> 4;   // edge within group of 4

    const int ngroups = N_EDGES / 4;          // 200000 exact
    const int nw      = gridDim.x * 4;
    for (int g = blockIdx.x * 4 + wave; g < ngroups; g += nw) {
        const int e = g * 4 + ei;
        int pos = 0;
        if (q == 0) pos = atomicAdd(&cursor[dst[(long)e << ish]], 1);
        pos = __shfl(pos, lane & 48, 64);

        bf16x8 v;
        if (q < 8) {
            const int s_ = src[(long)e << ish];
            v = tbl ? *(const bf16x8*)((const bf16*)nfsrc + (size_t)s_ * 64 + q * 8)
                    : load8(nfsrc, (long)s_ * 64 + q * 8, f32);
        } else {
            v = load8(efeats, (long)e * 64 + (q - 8) * 8, f32);
        }
        *(bf16x8*)(A + (size_t)pos * 128 + q * 8) = v;
    }
}

// ---------------------------------------------------------------------------
// Dense fused message + aggregate: one wave per dst node, A is the pre-built
// CSR-ordered [E][128] bf16 matrix -> pure streaming reads. W staged with
// k-strided loads + b128 LDS writes (bank-group-uniform; kills the 16-way
// staging conflicts seen in round 1).
// ---------------------------------------------------------------------------
__global__ __launch_bounds__(256) void msg_agg_dense(
    const void* __restrict__ nfeats,      // only for dtype detection
    const bf16* __restrict__ A,
    const void* __restrict__ W_msg,
    const void* __restrict__ b_msg,
    const int*  __restrict__ row_ptr,
    float*      __restrict__ h_neigh)
{
    __shared__ bf16 sWT[128 * 136];       // [n][k], stride 272 B (16-aligned)
    __shared__ int s_flags;

    const int tid = threadIdx.x;
    if (tid == 0) s_flags = detect_f32(nfeats) ? 1 : 0;
    __syncthreads();
    const bool f32 = (s_flags & 1) != 0;

    // k-strided staging: task -> (n = task&127, kb8 = task>>7), one b128 write
    #pragma unroll
    for (int it = 0; it < 8; ++it) {
        const int task = it * 256 + tid;
        const int n    = task & 127;
        const int kb8  = task >> 7;       // 0..15
        bf16x8 w;
        #pragma unroll
        for (int j = 0; j < 8; ++j)
            w[j] = (bf16)loadf(W_msg, (long)(kb8 * 8 + j) * 128 + n, f32);
        *(bf16x8*)(sWT + n * 136 + kb8 * 8) = w;
    }
    __syncthreads();

    const int wave = tid >> 6;
    const int lane = tid & 63;
    const int m    = lane & 15;
    const int quad = lane >> 4;

    float bias[8];
    #pragma unroll
    for (int t = 0; t < 8; ++t) bias[t] = loadf(b_msg, t * 16 + m, f32);

    const int wstride = gridDim.x * 4;
    for (int v = blockIdx.x * 4 + wave; v < N_NODES; v += wstride) {
        const int beg = row_ptr[v];
        const int deg = row_ptr[v + 1] - beg;

        float hacc[8] = {0.f, 0.f, 0.f, 0.f, 0.f, 0.f, 0.f, 0.f};

        for (int T = 0; T * 16 < deg; ++T) {
            const int r0 = T * 16;
            const int sl = (r0 + m < deg) ? (beg + r0 + m) : beg;
            const bf16* ap = A + (size_t)sl * 128 + quad * 8;

            bf16x8 a[4];
            #pragma unroll
            for (int kb = 0; kb < 4; ++kb)
                a[kb] = *(const bf16x8*)(ap + kb * 32);

            #pragma unroll
            for (int t = 0; t < 8; ++t) {
                f32x4 acc = {0.f, 0.f, 0.f, 0.f};
                const bf16* bp = sWT + (t * 16 + m) * 136 + quad * 8;
                #pragma unroll
                for (int kb = 0; kb < 4; ++kb)
                    acc = __builtin_amdgcn_mfma_f32_16x16x32_bf16(
                              a[kb], *(const bf16x8*)(bp + kb * 32), acc, 0, 0, 0);
                float part = 0.f;
                #pragma unroll
                for (int i = 0; i < 4; ++i) {
                    float val = acc[i] + bias[t];
                    val = val > 0.f ? val : 0.f;
                    if (r0 + quad * 4 + i < deg) part += val;
                }
                hacc[t] += part;
            }
        }

        #pragma unroll
        for (int t = 0; t < 8; ++t) {
            float s = hacc[t];
            s += __shfl_xor(s, 16, 64);
            s += __shfl_xor(s, 32, 64);
            hacc[t] = s;
        }

        const float lo = quad < 2 ? (quad == 0 ? hacc[0] : hacc[1])
                                  : (quad == 2 ? hacc[2] : hacc[3]);
        const float hi = quad < 2 ? (quad == 0 ? hacc[4] : hacc[5])
                                  : (quad == 2 ? hacc[6] : hacc[7]);
        h_neigh[(size_t)v * 128 + lane]      = lo;
        h_neigh[(size_t)v * 128 + 64 + lane] = hi;
    }
}

// ---------------------------------------------------------------------------
// Fallback CSR path (verified round-1): scatter edge ids, gather in msg_agg.
// ---------------------------------------------------------------------------
__global__ __launch_bounds__(256) void scatter_kernel(const int* __restrict__ src,
                                                      const int* __restrict__ dst,
                                                      int* __restrict__ cursor,
                                                      int* __restrict__ eid,
                                                      int* __restrict__ srcs) {
    __shared__ int s_ish;
    if (threadIdx.x == 0) s_ish = detect_i64(dst) ? 1 : 0;
    __syncthreads();
    const int ish = s_ish;
    const int stride = gridDim.x * blockDim.x;
    for (int e = blockIdx.x * blockDim.x + threadIdx.x; e < N_EDGES; e += stride) {
        const int d = dst[(long)e << ish];
        const int pos = atomicAdd(&cursor[d], 1);
        eid[pos]  = e;
        srcs[pos] = src[(long)e << ish];
    }
}

__global__ __launch_bounds__(256) void msg_agg_kernel(
    const void* __restrict__ nfeats,
    const void* __restrict__ efeats,
    const void* __restrict__ W_msg,
    const void* __restrict__ b_msg,
    const int*  __restrict__ row_ptr,
    const int*  __restrict__ eid,
    const int*  __restrict__ srcs,
    float*      __restrict__ h_neigh)
{
    __shared__ bf16 sWT[128 * 136];
    __shared__ int s_flags;

    const int tid = threadIdx.x;
    if (tid == 0) s_flags = detect_f32(nfeats) ? 1 : 0;
    __syncthreads();
    const bool f32 = (s_flags & 1) != 0;

    #pragma unroll
    for (int it = 0; it < 8; ++it) {
        const int task = it * 256 + tid;
        const int k = task >> 4;
        const int c = task & 15;
        const bf16x8 w = load8(W_msg, (long)k * 128 + c * 8, f32);
        #pragma unroll
        for (int u = 0; u < 8; ++u) sWT[(c * 8 + u) * 136 + k] = w[u];
    }
    __syncthreads();

    const int wave = tid >> 6;
    const int lane = tid & 63;
    const int m    = lane & 15;
    const int quad = lane >> 4;

    float bias[8];
    #pragma unroll
    for (int t = 0; t < 8; ++t) bias[t] = loadf(b_msg, t * 16 + m, f32);

    const int wstride = gridDim.x * 4;
    for (int v = blockIdx.x * 4 + wave; v < N_NODES; v += wstride) {
        const int beg = row_ptr[v];
        const int deg = row_ptr[v + 1] - beg;

        float hacc[8] = {0.f, 0.f, 0.f, 0.f, 0.f, 0.f, 0.f, 0.f};

        for (int T = 0; T * 16 < deg; ++T) {
            const int r0 = T * 16;
            const int sl = (r0 + m < deg) ? (beg + r0 + m) : beg;
            const int s  = srcs[sl];
            const int e  = eid[sl];

            bf16x8 a[4];
            a[0] = load8(nfeats, (long)s * 64 +      quad * 8, f32);
            a[1] = load8(nfeats, (long)s * 64 + 32 + quad * 8, f32);
            a[2] = load8(efeats, (long)e * 64 +      quad * 8, f32);
            a[3] = load8(efeats, (long)e * 64 + 32 + quad * 8, f32);

            #pragma unroll
            for (int t = 0; t < 8; ++t) {
                f32x4 acc = {0.f, 0.f, 0.f, 0.f};
                const bf16* bp = sWT + (t * 16 + m) * 136 + quad * 8;
                #pragma unroll
                for (int kb = 0; kb < 4; ++kb)
                    acc = __builtin_amdgcn_mfma_f32_16x16x32_bf16(
                              a[kb], *(const bf16x8*)(bp + kb * 32), acc, 0, 0, 0);
                float part = 0.f;
                #pragma unroll
                for (int i = 0; i < 4; ++i) {
                    float val = acc[i] + bias[t];
                    val = val > 0.f ? val : 0.f;
                    if (r0 + quad * 4 + i < deg) part += val;
                }
                hacc[t] += part;
            }
        }

        #pragma unroll
        for (int t = 0; t < 8; ++t) {
            float s = hacc[t];
            s += __shfl_xor(s, 16, 64);
            s += __shfl_xor(s, 32, 64);
            hacc[t] = s;
        }

        const float lo = quad < 2 ? (quad == 0 ? hacc[0] : hacc[1])
                                  : (quad == 2 ? hacc[2] : hacc[3]);
        const float hi = quad < 2 ? (quad == 0 ? hacc[4] : hacc[5])
                                  : (quad == 2 ? hacc[6] : hacc[7]);
        h_neigh[(size_t)v * 128 + lane]      = lo;
        h_neigh[(size_t)v * 128 + 64 + lane] = hi;
    }
}

// ---------------------------------------------------------------------------
// Last-resort fallback (verified round-0): per-edge messages + fp32 atomics.
// ---------------------------------------------------------------------------
__global__ __launch_bounds__(256) void edge_msg_kernel(
    const void* __restrict__ nfeats,
    const void* __restrict__ efeats,
    const void* __restrict__ W_msg,
    const void* __restrict__ b_msg,
    const int*  __restrict__ src,
    const int*  __restrict__ dst,
    float*      __restrict__ h_neigh)
{
    __shared__ bf16 sWT[128 * 136];
    __shared__ int s_flags;

    const int tid = threadIdx.x;
    if (tid == 0)
        s_flags = (detect_f32(nfeats) ? 1 : 0) | (detect_i64(dst) ? 2 : 0);
    __syncthreads();
    const bool f32 = (s_flags & 1) != 0;
    const int  ish = (s_flags & 2) ? 1 : 0;

    #pragma unroll
    for (int it = 0; it < 8; ++it) {
        const int task = it * 256 + tid;
        const int k = task >> 4;
        const int c = task & 15;
        const bf16x8 w = load8(W_msg, (long)k * 128 + c * 8, f32);
        #pragma unroll
        for (int u = 0; u < 8; ++u) sWT[(c * 8 + u) * 136 + k] = w[u];
    }
    __syncthreads();

    const int wave = tid >> 6;
    const int lane = tid & 63;
    const int m    = lane & 15;
    const int quad = lane >> 4;

    const int nchunks = N_EDGES / 64;
    for (int chunk = blockIdx.x; chunk < nchunks; chunk += gridDim.x) {
        const int ebase = chunk * 64 + wave * 16;
        const int e_m   = ebase + m;
        const int s     = src[(long)e_m << ish];

        bf16x8 a[4];
        a[0] = load8(nfeats, (long)s   * 64 +      quad * 8, f32);
        a[1] = load8(nfeats, (long)s   * 64 + 32 + quad * 8, f32);
        a[2] = load8(efeats, (long)e_m * 64 +      quad * 8, f32);
        a[3] = load8(efeats, (long)e_m * 64 + 32 + quad * 8, f32);

        int drow[4];
        #pragma unroll
        for (int i = 0; i < 4; ++i)
            drow[i] = dst[(long)(ebase + quad * 4 + i) << ish] * 128;

        #pragma unroll
        for (int t = 0; t < 8; ++t) {
            f32x4 acc = {0.f, 0.f, 0.f, 0.f};
            const bf16* bp = sWT + (t * 16 + m) * 136 + quad * 8;
            #pragma unroll
            for (int kb = 0; kb < 4; ++kb)
                acc = __builtin_amdgcn_mfma_f32_16x16x32_bf16(
                          a[kb], *(const bf16x8*)(bp + kb * 32), acc, 0, 0, 0);
            const int   n    = t * 16 + m;
            const float bias = loadf(b_msg, n, f32);
            #pragma unroll
            for (int i = 0; i < 4; ++i) {
                float v = acc[i] + bias;
                v = v > 0.f ? v : 0.f;
                unsafeAtomicAdd(h_neigh + drow[i] + n, v);
            }
        }
    }
}

// ---------------------------------------------------------------------------
// Kernel B: out = relu([nfeats, h_neigh] @ W_apply + b_apply), K=192.
// W staged k-strided (conflict-free b128 LDS writes).
// ---------------------------------------------------------------------------
__global__ __launch_bounds__(256) void apply_kernel(
    const void*  __restrict__ nfeats,
    const float* __restrict__ h_neigh,
    const void*  __restrict__ W_apply,
    const void*  __restrict__ b_apply,
    void*        __restrict__ out)
{
    __shared__ bf16 sWT[128 * 200];   // [n][k], k<192, stride 400 B (16-aligned)
    __shared__ int s_flags;

    const int tid = threadIdx.x;
    if (tid == 0) s_flags = detect_f32(nfeats) ? 1 : 0;
    __syncthreads();
    const bool f32 = (s_flags & 1) != 0;

    // k-strided staging: 3072 tasks = 128 n x 24 kb8-blocks
    #pragma unroll
    for (int it = 0; it < 12; ++it) {
        const int task = it * 256 + tid;
        const int n    = task & 127;
        const int kb8  = task >> 7;       // 0..23
        bf16x8 w;
        #pragma unroll
        for (int j = 0; j < 8; ++j)
            w[j] = (bf16)loadf(W_apply, (long)(kb8 * 8 + j) * 128 + n, f32);
        *(bf16x8*)(sWT + n * 200 + kb8 * 8) = w;
    }
    __syncthreads();

    const int wave = tid >> 6;
    const int lane = tid & 63;
    const int m    = lane & 15;
    const int quad = lane >> 4;

    const int nchunks = (N_NODES + 63) / 64;
    for (int chunk = blockIdx.x; chunk < nchunks; chunk += gridDim.x) {
        const int nbase = chunk * 64 + wave * 16;
        const int nm  = nbase + m;
        const int nmc = nm < N_NODES ? nm : N_NODES - 1;

        bf16x8 a[6];
        a[0] = load8(nfeats, (long)nmc * 64 +      quad * 8, f32);
        a[1] = load8(nfeats, (long)nmc * 64 + 32 + quad * 8, f32);
        #pragma unroll
        for (int kb = 0; kb < 4; ++kb) {
            const float* hp = h_neigh + (size_t)nmc * 128 + kb * 32 + quad * 8;
            const f32x4 p = *(const f32x4*)(hp);
            const f32x4 q = *(const f32x4*)(hp + 4);
            bf16x8 r;
            #pragma unroll
            for (int u = 0; u < 4; ++u) { r[u] = (bf16)p[u]; r[4 + u] = (bf16)q[u]; }
            a[2 + kb] = r;
        }

        #pragma unroll
        for (int t = 0; t < 8; ++t) {
            f32x4 acc = {0.f, 0.f, 0.f, 0.f};
            const bf16* bp = sWT + (t * 16 + m) * 200 + quad * 8;
            #pragma unroll
            for (int kb = 0; kb < 6; ++kb)
                acc = __builtin_amdgcn_mfma_f32_16x16x32_bf16(
                          a[kb], *(const bf16x8*)(bp + kb * 32), acc, 0, 0, 0);
            const int   n    = t * 16 + m;
            const float bias = loadf(b_apply, n, f32);
            #pragma unroll
            for (int i = 0; i < 4; ++i) {
                const int row = nbase + quad * 4 + i;
                if (row < N_NODES) {
                    float v = acc[i] + bias;
                    v = v > 0.f ? v : 0.f;
                    storef(out, (long)row * 128 + n, v, f32);
                }
            }
        }
    }
}

extern "C" void kernel_launch(void* const* d_in, const int* in_sizes, int n_in,
                              void* d_out, int out_size, void* d_ws, size_t ws_size,
                              hipStream_t stream) {
    const void* nfeats  = d_in[0];
    const void* efeats  = d_in[1];
    const void* W_msg   = d_in[2];
    const void* b_msg   = d_in[3];
    const void* W_apply = d_in[4];
    const void* b_apply = d_in[5];
    const int*  src     = (const int*)d_in[6];
    const int*  dst     = (const int*)d_in[7];

    float* h_neigh = (float*)d_ws;                        // 25,600,000 B

    // workspace layout (256B-aligned blocks)
    const size_t SZ_PAD     = 213248;                     // 53248 ints, padded
    const size_t OFF_ROWPTR = 25600000;
    const size_t OFF_CNT    = OFF_ROWPTR + SZ_PAD;        // counts -> cursor
    const size_t OFF_A      = OFF_CNT + SZ_PAD;           // dense path
    const size_t SZ_A       = (size_t)N_EDGES * 128 * 2;  // 204.8 MB
    const size_t OFF_NF     = OFF_A + SZ_A;               // bf16 nfeats table
    const size_t NEED_DENSE = OFF_A + SZ_A;               // 230.8 MB (no table)
    const size_t NEED_TBL   = OFF_NF + (size_t)N_NODES * 64 * 2;  // 237.2 MB
    const size_t OFF_EID    = OFF_A;                      // CSR fallback path
    const size_t OFF_SRCS   = OFF_EID + 3200000;
    const size_t NEED_CSR   = OFF_SRCS + 3200000;         // 32.4 MB

    int* row_ptr = (int*)((char*)d_ws + OFF_ROWPTR);
    int* cnt     = (int*)((char*)d_ws + OFF_CNT);

    if (ws_size >= NEED_DENSE) {
        bf16* A   = (bf16*)((char*)d_ws + OFF_A);
        const int tbl = (ws_size >= NEED_TBL) ? 1 : 0;
        bf16* nft = (bf16*)((char*)d_ws + OFF_NF);

        hipMemsetAsync(cnt, 0, (size_t)53248 * sizeof(int), stream);
        if (tbl) nf2bf_kernel<<<1563, 256, 0, stream>>>(nfeats, nft);
        hist_kernel<<<1024, 256, 0, stream>>>(dst, cnt);
        scan_kernel<<<1, 1024, 0, stream>>>(cnt, row_ptr);
        gather_kernel<<<2048, 256, 0, stream>>>(tbl ? (const void*)nft : nfeats,
                                                efeats, src, dst, cnt, A, tbl);
        msg_agg_dense<<<1024, 256, 0, stream>>>(nfeats, A, W_msg, b_msg,
                                                row_ptr, h_neigh);
    } else if (ws_size >= NEED_CSR) {
        int* eid  = (int*)((char*)d_ws + OFF_EID);
        int* srcs = (int*)((char*)d_ws + OFF_SRCS);
        hipMemsetAsync(cnt, 0, (size_t)53248 * sizeof(int), stream);
        hist_kernel<<<1024, 256, 0, stream>>>(dst, cnt);
        scan_kernel<<<1, 1024, 0, stream>>>(cnt, row_ptr);
        scatter_kernel<<<1024, 256, 0, stream>>>(src, dst, cnt, eid, srcs);
        msg_agg_kernel<<<1024, 256, 0, stream>>>(nfeats, efeats, W_msg, b_msg,
                                                 row_ptr, eid, srcs, h_neigh);
    } else {
        hipMemsetAsync(h_neigh, 0, (size_t)N_NODES * NDIM_OUT * sizeof(float), stream);
        edge_msg_kernel<<<768, 256, 0, stream>>>(nfeats, efeats, W_msg, b_msg,
                                                 src, dst, h_neigh);
    }

    apply_kernel<<<782, 256, 0, stream>>>(nfeats, h_neigh, W_apply, b_apply, d_out);
}